// Round 3
// baseline (233.427 us; speedup 1.0000x reference)
//
#include <hip/hip_runtime.h>

typedef __attribute__((ext_vector_type(8))) short bf16x8;
typedef __attribute__((ext_vector_type(16))) float f32x16;

__device__ __forceinline__ unsigned short f2b(float f) {
  unsigned x = __builtin_bit_cast(unsigned, f);
  x += 0x7fffu + ((x >> 16) & 1u);   // round-to-nearest-even
  return (unsigned short)(x >> 16);
}

// ---------------------------------------------------------------------------
// Kernel 0: W [768][384] fp32 -> Wt [384][768] bf16 (k-contiguous B-frags)
//           Y [128][384] fp32 -> Ybf bf16 + y2[l] fp32
// ---------------------------------------------------------------------------
__global__ __launch_bounds__(256) void k_prep(const float* __restrict__ W,
                                              const float* __restrict__ Y,
                                              unsigned short* __restrict__ Wt,
                                              unsigned short* __restrict__ Ybf,
                                              float* __restrict__ y2) {
  __shared__ unsigned short sT[64][72];
  int b = blockIdx.x;
  if (b < 72) {
    int bk = (b % 12) * 64, bn = (b / 12) * 64;
    int c = threadIdx.x & 63, rr = threadIdx.x >> 6;
#pragma unroll
    for (int i = 0; i < 16; i++) {
      int row = rr * 16 + i;
      sT[row][c] = f2b(W[(size_t)(bk + row) * 384 + bn + c]);
    }
    __syncthreads();
#pragma unroll
    for (int i = 0; i < 16; i++) {
      int row = rr * 16 + i;
      Wt[(size_t)(bn + row) * 768 + bk + c] = sT[c][row];
    }
  } else {
    int t = threadIdx.x;
    // Y -> bf16 (49152 elements = 12288 float4)
    for (int i = t; i < 12288; i += 256) {
      float4 v = ((const float4*)Y)[i];
      ushort4 o;
      o.x = f2b(v.x); o.y = f2b(v.y); o.z = f2b(v.z); o.w = f2b(v.w);
      ((ushort4*)Ybf)[i] = o;
    }
    if (t < 128) {
      const float4* row = (const float4*)(Y + (size_t)t * 384);
      float s = 0.f;
#pragma unroll
      for (int j = 0; j < 96; j++) {
        float4 v = row[j];
        s += v.x * v.x + v.y * v.y + v.z * v.z + v.w * v.w;
      }
      y2[t] = s;
    }
  }
}

// ---------------------------------------------------------------------------
// Kernel 1: projected = cls @ W + b  (fused expmap0), outputs fp32 x + fp32 x2
//   block: 128 rows x 384 cols, 512 threads (8 waves)
//   wave tile: 64 x 96 = 2x3 tiles of 32x32 (mfma_f32_32x32x16_bf16)
// ---------------------------------------------------------------------------
#define LDS1 72  // 64 + 8 pad; 144 B row stride

__global__ __launch_bounds__(512, 2) void k_proj(const float* __restrict__ cls,
                                                 const unsigned short* __restrict__ Wt,
                                                 const float* __restrict__ bias,
                                                 float* __restrict__ xout,
                                                 float* __restrict__ x2out) {
  __shared__ unsigned short sA[128 * LDS1];  // 18432 B
  __shared__ unsigned short sW[384 * LDS1];  // 55296 B
  __shared__ float rs[128][4];
  __shared__ float sF[128];

  const int tid = threadIdx.x;
  const int bm = blockIdx.x * 128;
  const int wave = tid >> 6, lane = tid & 63;
  const int r = lane & 31, h = lane >> 5;
  const int rg = wave & 1, cg = wave >> 1;  // rows rg*64, cols cg*96

  f32x16 acc[2][3];
#pragma unroll
  for (int i = 0; i < 2; i++)
#pragma unroll
    for (int j = 0; j < 3; j++)
#pragma unroll
      for (int e = 0; e < 16; e++) acc[i][j][e] = 0.f;

  for (int k0 = 0; k0 < 768; k0 += 64) {
    __syncthreads();
#pragma unroll
    for (int c = tid; c < 1024; c += 512) {  // A: 128x64, fp32 -> bf16
      int row = c >> 3, kc = c & 7;
      const float* src = cls + (size_t)(bm + row) * 768 + k0 + kc * 8;
      float4 f0 = *(const float4*)(src);
      float4 f1 = *(const float4*)(src + 4);
      uint4 p;
      p.x = (unsigned)f2b(f0.x) | ((unsigned)f2b(f0.y) << 16);
      p.y = (unsigned)f2b(f0.z) | ((unsigned)f2b(f0.w) << 16);
      p.z = (unsigned)f2b(f1.x) | ((unsigned)f2b(f1.y) << 16);
      p.w = (unsigned)f2b(f1.z) | ((unsigned)f2b(f1.w) << 16);
      *(uint4*)(sA + row * LDS1 + kc * 8) = p;
    }
#pragma unroll
    for (int c = tid; c < 3072; c += 512) {  // Wt: 384x64 bf16
      int row = c >> 3, kc = c & 7;
      *(uint4*)(sW + row * LDS1 + kc * 8) =
          *(const uint4*)(Wt + (size_t)row * 768 + k0 + kc * 8);
    }
    __syncthreads();
#pragma unroll
    for (int sub = 0; sub < 4; sub++) {
      const int kk = sub * 16 + h * 8;
      bf16x8 a0 = *(const bf16x8*)(sA + (rg * 64 + r) * LDS1 + kk);
      bf16x8 a1 = *(const bf16x8*)(sA + (rg * 64 + 32 + r) * LDS1 + kk);
      bf16x8 b0 = *(const bf16x8*)(sW + (cg * 96 + r) * LDS1 + kk);
      bf16x8 b1 = *(const bf16x8*)(sW + (cg * 96 + 32 + r) * LDS1 + kk);
      bf16x8 b2 = *(const bf16x8*)(sW + (cg * 96 + 64 + r) * LDS1 + kk);
      acc[0][0] = __builtin_amdgcn_mfma_f32_32x32x16_bf16(a0, b0, acc[0][0], 0, 0, 0);
      acc[0][1] = __builtin_amdgcn_mfma_f32_32x32x16_bf16(a0, b1, acc[0][1], 0, 0, 0);
      acc[0][2] = __builtin_amdgcn_mfma_f32_32x32x16_bf16(a0, b2, acc[0][2], 0, 0, 0);
      acc[1][0] = __builtin_amdgcn_mfma_f32_32x32x16_bf16(a1, b0, acc[1][0], 0, 0, 0);
      acc[1][1] = __builtin_amdgcn_mfma_f32_32x32x16_bf16(a1, b1, acc[1][1], 0, 0, 0);
      acc[1][2] = __builtin_amdgcn_mfma_f32_32x32x16_bf16(a1, b2, acc[1][2], 0, 0, 0);
    }
  }

  // bias add + per-row sum of squares (wave covers 96 of 384 cols)
  float bcol[3];
#pragma unroll
  for (int j = 0; j < 3; j++) bcol[j] = bias[cg * 96 + j * 32 + r];

#pragma unroll
  for (int i = 0; i < 2; i++) {
#pragma unroll
    for (int reg = 0; reg < 16; reg++) {
      float s = 0.f;
#pragma unroll
      for (int j = 0; j < 3; j++) {
        float v = acc[i][j][reg] + bcol[j];
        acc[i][j][reg] = v;
        s += v * v;
      }
      s += __shfl_xor(s, 1);
      s += __shfl_xor(s, 2);
      s += __shfl_xor(s, 4);
      s += __shfl_xor(s, 8);
      s += __shfl_xor(s, 16);
      if (r == 0) {
        int rowl = rg * 64 + i * 32 + (reg & 3) + 8 * (reg >> 2) + 4 * h;
        rs[rowl][cg] = s;
      }
    }
  }
  __syncthreads();
  if (tid < 128) {
    float n2 = rs[tid][0] + rs[tid][1] + rs[tid][2] + rs[tid][3];
    float n = fmaxf(sqrtf(n2), 1e-15f);
    float f = tanhf(n) / n;
    sF[tid] = f;
    x2out[bm + tid] = n2 * f * f;  // fp32 x2 (clip-sensitivity)
  }
  __syncthreads();
#pragma unroll
  for (int i = 0; i < 2; i++) {
#pragma unroll
    for (int reg = 0; reg < 16; reg++) {
      int rowl = rg * 64 + i * 32 + (reg & 3) + 8 * (reg >> 2) + 4 * h;
      float f = sF[rowl];
#pragma unroll
      for (int j = 0; j < 3; j++) {
        xout[(size_t)(bm + rowl) * 384 + cg * 96 + j * 32 + r] = acc[i][j][reg] * f;
      }
    }
  }
}

// ---------------------------------------------------------------------------
// Kernel 2: xy = x @ y^T + fused Poincare distance epilogue (fp32 in/out)
//   block: 128 rows x 128 cols, 512 threads (8 waves)
//   x fp32 -> bf16 conversion fused into LDS staging
// ---------------------------------------------------------------------------
#define LDS2 136  // 128 + 8 pad; 272 B row stride

__global__ __launch_bounds__(512, 4) void k_logits(const float* __restrict__ X,
                                                   const float* __restrict__ x2,
                                                   const unsigned short* __restrict__ Y,
                                                   const float* __restrict__ y2,
                                                   float* __restrict__ out) {
  __shared__ unsigned short sX[128 * LDS2];
  __shared__ unsigned short sY[128 * LDS2];
  const int tid = threadIdx.x;
  const int bm = blockIdx.x * 128;
  const int wave = tid >> 6, lane = tid & 63;
  const int r = lane & 31, h = lane >> 5;
  const int rt = 32 * (wave & 3), ct = 64 * (wave >> 2);

  f32x16 acc[2];
#pragma unroll
  for (int j = 0; j < 2; j++)
#pragma unroll
    for (int e = 0; e < 16; e++) acc[j][e] = 0.f;

  for (int k0 = 0; k0 < 384; k0 += 128) {
    __syncthreads();
#pragma unroll
    for (int c = tid; c < 2048; c += 512) {  // X: 128x128 fp32 -> bf16
      int row = c >> 4, kc = c & 15;
      const float* src = X + (size_t)(bm + row) * 384 + k0 + kc * 8;
      float4 f0 = *(const float4*)(src);
      float4 f1 = *(const float4*)(src + 4);
      uint4 p;
      p.x = (unsigned)f2b(f0.x) | ((unsigned)f2b(f0.y) << 16);
      p.y = (unsigned)f2b(f0.z) | ((unsigned)f2b(f0.w) << 16);
      p.z = (unsigned)f2b(f1.x) | ((unsigned)f2b(f1.y) << 16);
      p.w = (unsigned)f2b(f1.z) | ((unsigned)f2b(f1.w) << 16);
      *(uint4*)(sX + row * LDS2 + kc * 8) = p;
    }
#pragma unroll
    for (int c = tid; c < 2048; c += 512) {  // Ybf: 128x128 bf16
      int row = c >> 4, kc = c & 15;
      *(uint4*)(sY + row * LDS2 + kc * 8) =
          *(const uint4*)(Y + (size_t)row * 384 + k0 + kc * 8);
    }
    __syncthreads();
#pragma unroll
    for (int sub = 0; sub < 8; sub++) {
      const int kk = sub * 16 + h * 8;
      bf16x8 a = *(const bf16x8*)(sX + (rt + r) * LDS2 + kk);
      bf16x8 b0 = *(const bf16x8*)(sY + (ct + r) * LDS2 + kk);
      bf16x8 b1 = *(const bf16x8*)(sY + (ct + 32 + r) * LDS2 + kk);
      acc[0] = __builtin_amdgcn_mfma_f32_32x32x16_bf16(a, b0, acc[0], 0, 0, 0);
      acc[1] = __builtin_amdgcn_mfma_f32_32x32x16_bf16(a, b1, acc[1], 0, 0, 0);
    }
  }

  const float CLIP = 0.9999800001f;  // (1 - 1e-5)^2
  float yc[2] = {y2[ct + r], y2[ct + 32 + r]};
#pragma unroll
  for (int reg = 0; reg < 16; reg++) {
    int rowl = rt + (reg & 3) + 8 * (reg >> 2) + 4 * h;
    float xr = x2[bm + rowl];
#pragma unroll
    for (int j = 0; j < 2; j++) {
      float xy = acc[j][reg];
      float sq = xr + yc[j] - 2.f * xy;
      float den = 1.f - 2.f * xy + xr * yc[j];
      float ratio = fminf(fmaxf(sq / den, 0.f), CLIP);
      float s = sqrtf(ratio);
      float dist = logf((1.f + s) / (1.f - s));  // 2*atanh(s)
      out[(size_t)(bm + rowl) * 128 + ct + j * 32 + r] = -dist;
    }
  }
}

// ---------------------------------------------------------------------------
extern "C" void kernel_launch(void* const* d_in, const int* in_sizes, int n_in,
                              void* d_out, int out_size, void* d_ws, size_t ws_size,
                              hipStream_t stream) {
  const float* cls  = (const float*)d_in[0];  // [32768][768] fp32
  const float* W    = (const float*)d_in[1];  // [768][384] fp32
  const float* bias = (const float*)d_in[2];  // [384] fp32
  const float* Y    = (const float*)d_in[3];  // [128][384] fp32

  float* out_logits = (float*)d_out;                    // [32768][128] fp32
  float* out_x = out_logits + (size_t)32768 * 128;      // [32768][384] fp32

  float* x2 = (float*)d_ws;                           // 32768 fp32
  float* y2 = x2 + 32768;                             // 128 fp32
  unsigned short* Wt = (unsigned short*)(y2 + 128);   // [384][768] bf16
  unsigned short* Ybf = Wt + (size_t)384 * 768;       // [128][384] bf16

  k_prep<<<73, 256, 0, stream>>>(W, Y, Wt, Ybf, y2);
  k_proj<<<256, 512, 0, stream>>>(cls, Wt, bias, out_x, x2);
  k_logits<<<256, 512, 0, stream>>>(out_x, x2, Ybf, y2, out_logits);
}